// Round 6
// baseline (336.158 us; speedup 1.0000x reference)
//
#include <hip/hip_runtime.h>

typedef unsigned short u16;
typedef unsigned int u32;
typedef __bf16 bf16x8 __attribute__((ext_vector_type(8)));
typedef float f32x4 __attribute__((ext_vector_type(4)));
typedef u16 u16x8 __attribute__((ext_vector_type(8)));

__device__ __forceinline__ u16 f2bf(float f) {
  u32 u = __builtin_bit_cast(u32, f);
  u += 0x7FFFu + ((u >> 16) & 1u);   // round-to-nearest-even
  return (u16)(u >> 16);
}
__device__ __forceinline__ float bf2f(u16 h) {
  u32 u = ((u32)h) << 16;
  return __builtin_bit_cast(float, u);
}

// async global->LDS, 16B per lane, linear dest (wave-uniform base + lane*16)
#define GLD16(gp, lp)                                                      \
  __builtin_amdgcn_global_load_lds(                                        \
      (const __attribute__((address_space(1))) void*)(gp),                 \
      (__attribute__((address_space(3))) void*)(lp), 16, 0, 0)

#define LGKM0()                                          \
  do {                                                   \
    asm volatile("s_waitcnt lgkmcnt(0)" ::: "memory");   \
    __builtin_amdgcn_sched_barrier(0);                   \
  } while (0)
#define VMCNT(n)                                              \
  do {                                                        \
    asm volatile("s_waitcnt vmcnt(" #n ")" ::: "memory");     \
    __builtin_amdgcn_sched_barrier(0);                        \
  } while (0)
#define BAR() __builtin_amdgcn_s_barrier()

// ---------------------------------------------------------------------------
// f32 -> bf16 elementwise convert, 8 elems/thread
__global__ void cvt_f32_bf16(const float* __restrict__ in, u16* __restrict__ out, int n8) {
  int i = blockIdx.x * 256 + threadIdx.x;
  if (i >= n8) return;
  const float4* p = (const float4*)in + (size_t)i * 2;
  float4 a = p[0], b = p[1];
  u16x8 o;
  o[0] = f2bf(a.x); o[1] = f2bf(a.y); o[2] = f2bf(a.z); o[3] = f2bf(a.w);
  o[4] = f2bf(b.x); o[5] = f2bf(b.y); o[6] = f2bf(b.z); o[7] = f2bf(b.w);
  *((u16x8*)out + i) = o;
}

// W1 (2048x2048 f32, [d][e]) -> W1t bf16 [e][d]  (tiled transpose)
__global__ void transpose_cvt(const float* __restrict__ W1, u16* __restrict__ W1t) {
  __shared__ float tile[32][33];
  const int tx = threadIdx.x;        // 0..31
  const int ty = threadIdx.y;        // 0..7
  const int e0 = blockIdx.x * 32, d0 = blockIdx.y * 32;
#pragma unroll
  for (int j = 0; j < 4; ++j)
    tile[ty + j * 8][tx] = W1[(size_t)(d0 + ty + j * 8) * 2048 + e0 + tx];
  __syncthreads();
#pragma unroll
  for (int j = 0; j < 4; ++j)
    W1t[(size_t)(e0 + ty + j * 8) * 2048 + d0 + tx] = f2bf(tile[tx][ty + j * 8]);
}

// U (K=8, D=2048, R=64 f32) -> Ut bf16 [d][k*64+r]   (B^T layout for GEMM3)
__global__ void make_Ut(const float* __restrict__ U, u16* __restrict__ Ut) {
  int idx = blockIdx.x * 256 + threadIdx.x;   // n*512 + (k*64+r), total 1048576
  int n = idx >> 9;
  int kr = idx & 511;
  int k = kr >> 6, r = kr & 63;
  Ut[idx] = f2bf(U[(size_t)k * 131072 + (size_t)n * 64 + r]);
}

// ---------------------------------------------------------------------------
// 256x256 8-phase bf16 MFMA GEMM (T2+T3+T4+T5): C[M,N] = A[M,Kd] @ Bt[N,Kd]^T
// 8 waves (2M x 4N), per-wave 128x64 output, BK=64, 128KiB double-buffered LDS.
// EPI 0: +bias, relu, bf16 out    EPI 2: f32 out
template <int EPI>
__launch_bounds__(512, 2)
__global__ void gemm256(const u16* __restrict__ A, const u16* __restrict__ Bt,
                        float* __restrict__ Cf, u16* __restrict__ Cb,
                        const float* __restrict__ bias, int M, int N, int Kd) {
  // [buf][half-tile: 0=Ah0 1=Ah1 2=Bh0 3=Bh1][128 rows x 64 elems]
  __shared__ u16 lds[2][4][8192];

  const int nbx = N >> 8;
  const int nwg = (M >> 8) * nbx;
  int wg = blockIdx.x;
  wg = (wg & 7) * (nwg >> 3) + (wg >> 3);       // XCD swizzle (nwg % 8 == 0)
  const int bx = wg % nbx, by = wg / nbx;
  const int bm = by << 8, bn = bx << 8;

  const int tid = threadIdx.x;
  const int lane = tid & 63, wave = tid >> 6;
  const int wr = wave >> 2;                      // 0..1  (A half)
  const int wc = wave & 3;                       // 0..3
  const int hc = 2 + (wc >> 1);                  // B half-tile index (2 or 3)
  const int l15 = lane & 15, hi = lane >> 4;
  const int swz = l15 & 7;

  // staging offsets: thread stages two 16B chunks per half-tile, LINEAR dest,
  // pre-swizzled global source column (involution: slot ^= row&7)
  const int scol = ((tid & 7) ^ ((tid >> 3) & 7)) << 3;
  const size_t goff0 = (size_t)(tid >> 3) * Kd + scol;
  const size_t goff1 = goff0 + (size_t)64 * Kd;
  const int d0e = tid * 8, d1e = tid * 8 + 4096;

  const int NT = Kd >> 6;

  // frag read element offsets (within one half-tile buffer)
  int aidx[8], bidx[4];
#pragma unroll
  for (int m = 0; m < 8; ++m) aidx[m] = (m * 16 + l15) * 64;
#pragma unroll
  for (int n = 0; n < 4; ++n) bidx[n] = ((wc & 1) * 64 + n * 16 + l15) * 64;
  const int slot0 = ((0 * 4 + hi) ^ swz) << 3;   // ksub 0
  const int slot1 = ((1 * 4 + hi) ^ swz) << 3;   // ksub 1

  f32x4 acc[8][4];
#pragma unroll
  for (int m = 0; m < 8; ++m)
#pragma unroll
    for (int n = 0; n < 4; ++n) acc[m][n] = f32x4{0.f, 0.f, 0.f, 0.f};

#define STAGE(tt, ht)                                                          \
  do {                                                                         \
    const u16* g_ = ((ht) < 2 ? A + (size_t)(bm + ((ht) & 1) * 128) * Kd       \
                              : Bt + (size_t)(bn + ((ht) & 1) * 128) * Kd)     \
                    + (size_t)(tt) * 64;                                       \
    u16* l_ = &lds[(tt) & 1][(ht)][0];                                         \
    GLD16(g_ + goff0, l_ + d0e);                                               \
    GLD16(g_ + goff1, l_ + d1e);                                               \
  } while (0)

#define MFMA2(av, bv, nA, nB)                                                  \
  _Pragma("unroll") for (int m = 0; m < 8; ++m) {                              \
    acc[m][nA] = __builtin_amdgcn_mfma_f32_16x16x32_bf16(av[m], bv[nA], acc[m][nA], 0, 0, 0); \
    acc[m][nB] = __builtin_amdgcn_mfma_f32_16x16x32_bf16(av[m], bv[nB], acc[m][nB], 0, 0, 0); \
  }

  // prologue: tile0 fully + Ah0,Ah1,Bh0 of tile1 (14 loads), then wait 8 oldest
  STAGE(0, 0); STAGE(0, 1); STAGE(0, 2); STAGE(0, 3);
  STAGE(1, 0); STAGE(1, 1); STAGE(1, 2);
  VMCNT(6);
  BAR();

  for (int t = 0; t < NT; ++t) {
    const int b = t & 1;
    const u16* As = &lds[b][wr][0];
    const u16* Bs = &lds[b][hc][0];
    bf16x8 av0[8], bv0[4], av1[8], bv1[4];

    // ---- phase 1: reads k0 (12x ds_read_b128) | stage Bh1(t+1) | MFMA k0 n0,n1
#pragma unroll
    for (int m = 0; m < 8; ++m) av0[m] = *(const bf16x8*)(As + aidx[m] + slot0);
#pragma unroll
    for (int n = 0; n < 4; ++n) bv0[n] = *(const bf16x8*)(Bs + bidx[n] + slot0);
    if (t + 1 < NT) STAGE(t + 1, 3);
    BAR();
    LGKM0();
    __builtin_amdgcn_s_setprio(1);
    MFMA2(av0, bv0, 0, 1);
    __builtin_amdgcn_s_setprio(0);
    BAR();

    // ---- phase 2: reads k1 | MFMA k0 n2,n3   (full drain -> tile t LDS free)
#pragma unroll
    for (int m = 0; m < 8; ++m) av1[m] = *(const bf16x8*)(As + aidx[m] + slot1);
#pragma unroll
    for (int n = 0; n < 4; ++n) bv1[n] = *(const bf16x8*)(Bs + bidx[n] + slot1);
    BAR();
    LGKM0();
    __builtin_amdgcn_s_setprio(1);
    MFMA2(av0, bv0, 2, 3);
    __builtin_amdgcn_s_setprio(0);
    BAR();

    // ---- phase 3: stage Ah0,Ah1(t+2) | MFMA k1 n0,n1
    if (t + 2 < NT) { STAGE(t + 2, 0); STAGE(t + 2, 1); }
    BAR();
    __builtin_amdgcn_s_setprio(1);
    MFMA2(av1, bv1, 0, 1);
    __builtin_amdgcn_s_setprio(0);
    BAR();

    // ---- phase 4: stage Bh0(t+2) | MFMA k1 n2,n3 | counted vmcnt
    if (t + 2 < NT) STAGE(t + 2, 2);
    BAR();
    __builtin_amdgcn_s_setprio(1);
    MFMA2(av1, bv1, 2, 3);
    __builtin_amdgcn_s_setprio(0);
    if (t < NT - 2) { VMCNT(6); }
    else if (t == NT - 2) { VMCNT(0); }
    BAR();
  }
#undef STAGE
#undef MFMA2

  // epilogue: C/D layout col=lane&15, row=(lane>>4)*4+reg  [m89-verified]
#pragma unroll
  for (int m = 0; m < 8; ++m) {
    const int row0 = bm + wr * 128 + m * 16 + hi * 4;
#pragma unroll
    for (int n = 0; n < 4; ++n) {
      const int col = bn + wc * 64 + n * 16 + l15;
      f32x4 v = acc[m][n];
      if (EPI == 0) {
        const float bsv = bias[col];
#pragma unroll
        for (int j = 0; j < 4; ++j) {
          float tv = v[j] + bsv;
          tv = tv > 0.f ? tv : 0.f;
          Cb[(size_t)(row0 + j) * N + col] = f2bf(tv);
        }
      } else {
#pragma unroll
        for (int j = 0; j < 4; ++j)
          Cf[(size_t)(row0 + j) * N + col] = v[j];
      }
    }
  }
}

// ---------------------------------------------------------------------------
// 128x128 bf16 MFMA GEMM (m97 structure) — kept for GEMM2 (N=512).
// EPI 1: *alpha[row, col/64], bf16 out
template <int EPI>
__launch_bounds__(256, 2)
__global__ void gemm_bt(const u16* __restrict__ A, const u16* __restrict__ Bt,
                        float* __restrict__ Cf, u16* __restrict__ Cb,
                        const float* __restrict__ bias, const float* __restrict__ alpha,
                        int M, int N, int Kd) {
  __shared__ u16 As[128 * 64];
  __shared__ u16 Bs[128 * 64];

  const int nbx = N >> 7;
  const int nwg = (M >> 7) * nbx;
  int wg = blockIdx.x;
  wg = (wg & 7) * (nwg >> 3) + (wg >> 3);
  const int bx = wg % nbx, by = wg / nbx;
  const int bm = by << 7, bn = bx << 7;

  const int tid = threadIdx.x;
  const int lane = tid & 63, wave = tid >> 6;
  const int wr = wave >> 1, wc = wave & 1;
  const int l15 = lane & 15, hi = lane >> 4;
  const int swz7 = l15 & 7;

  f32x4 acc[4][4];
#pragma unroll
  for (int m = 0; m < 4; ++m)
#pragma unroll
    for (int n = 0; n < 4; ++n)
      acc[m][n] = f32x4{0.f, 0.f, 0.f, 0.f};

  const int srow = tid >> 3;
  const int swzc = ((tid & 7) ^ (srow & 7)) << 3;
  const size_t ldsBase = (size_t)wave * 64 * 8;

  int aBase[4], bBase[4];
#pragma unroll
  for (int m = 0; m < 4; ++m) {
    aBase[m] = (wr * 64 + m * 16 + l15) * 64;
    bBase[m] = (wc * 64 + m * 16 + l15) * 64;
  }

  const u16* Ag = A + (size_t)(bm + srow) * Kd + swzc;
  const u16* Bg = Bt + (size_t)(bn + srow) * Kd + swzc;

  for (int k0 = 0; k0 < Kd; k0 += 64) {
#pragma unroll
    for (int i = 0; i < 4; ++i) {
      GLD16(Ag + (size_t)(i * 32) * Kd + k0, (u16*)As + i * 2048 + ldsBase);
      GLD16(Bg + (size_t)(i * 32) * Kd + k0, (u16*)Bs + i * 2048 + ldsBase);
    }
    __syncthreads();
#pragma unroll
    for (int kk = 0; kk < 2; ++kk) {
      const int soff = ((kk * 4 + hi) ^ swz7) << 3;
      bf16x8 av[4], bv[4];
#pragma unroll
      for (int m = 0; m < 4; ++m) av[m] = *(const bf16x8*)(As + aBase[m] + soff);
#pragma unroll
      for (int n = 0; n < 4; ++n) bv[n] = *(const bf16x8*)(Bs + bBase[n] + soff);
#pragma unroll
      for (int m = 0; m < 4; ++m)
#pragma unroll
        for (int n = 0; n < 4; ++n)
          acc[m][n] = __builtin_amdgcn_mfma_f32_16x16x32_bf16(av[m], bv[n], acc[m][n], 0, 0, 0);
    }
    __syncthreads();
  }

#pragma unroll
  for (int m = 0; m < 4; ++m) {
    const int row0 = bm + wr * 64 + m * 16 + hi * 4;
#pragma unroll
    for (int n = 0; n < 4; ++n) {
      const int col = bn + wc * 64 + n * 16 + l15;
      f32x4 v = acc[m][n];
      if (EPI == 1) {
        const int e = col >> 6;
#pragma unroll
        for (int j = 0; j < 4; ++j) {
          float t = v[j] * alpha[(size_t)(row0 + j) * 8 + e];
          Cb[(size_t)(row0 + j) * N + col] = f2bf(t);
        }
      } else {
#pragma unroll
        for (int j = 0; j < 4; ++j)
          Cf[(size_t)(row0 + j) * N + col] = v[j];
      }
    }
  }
}

// ---------------------------------------------------------------------------
// router: logits[i,e] = sum_d h[i,d]*W2[d,e] + b2[e]; alpha = softmax_e
__global__ void router(const u16* __restrict__ hb, const float* __restrict__ W2,
                       const float* __restrict__ b2, float* __restrict__ alphaOut) {
  const int row = blockIdx.x * 4 + (threadIdx.x >> 6);
  const int lane = threadIdx.x & 63;
  const u16* h = hb + (size_t)row * 2048;
  float a8[8] = {0.f, 0.f, 0.f, 0.f, 0.f, 0.f, 0.f, 0.f};
#pragma unroll
  for (int it = 0; it < 4; ++it) {
    const int d0 = it * 512 + lane * 8;
    u16x8 hv = *(const u16x8*)(h + d0);
#pragma unroll
    for (int jj = 0; jj < 8; ++jj) {
      const float hf = bf2f(hv[jj]);
      const float4* wp = (const float4*)(W2 + (size_t)(d0 + jj) * 8);
      float4 w0 = wp[0], w1 = wp[1];
      a8[0] += hf * w0.x; a8[1] += hf * w0.y; a8[2] += hf * w0.z; a8[3] += hf * w0.w;
      a8[4] += hf * w1.x; a8[5] += hf * w1.y; a8[6] += hf * w1.z; a8[7] += hf * w1.w;
    }
  }
#pragma unroll
  for (int off = 32; off; off >>= 1)
#pragma unroll
    for (int e = 0; e < 8; ++e) a8[e] += __shfl_xor(a8[e], off);
  if (lane == 0) {
    float mx = -1e30f;
#pragma unroll
    for (int e = 0; e < 8; ++e) { a8[e] += b2[e]; mx = a8[e] > mx ? a8[e] : mx; }
    float s = 0.f;
#pragma unroll
    for (int e = 0; e < 8; ++e) { a8[e] = __expf(a8[e] - mx); s += a8[e]; }
    const float inv = 1.f / s;
#pragma unroll
    for (int e = 0; e < 8; ++e) alphaOut[(size_t)row * 8 + e] = a8[e] * inv;
  }
}

// ---------------------------------------------------------------------------
extern "C" void kernel_launch(void* const* d_in, const int* in_sizes, int n_in,
                              void* d_out, int out_size, void* d_ws, size_t ws_size,
                              hipStream_t stream) {
  const float* x  = (const float*)d_in[0];
  const float* U  = (const float*)d_in[1];
  const float* V  = (const float*)d_in[2];
  const float* W1 = (const float*)d_in[3];
  const float* b1 = (const float*)d_in[4];
  const float* W2 = (const float*)d_in[5];
  const float* b2 = (const float*)d_in[6];
  float* out = (float*)d_out;

  char* w = (char*)d_ws;
  u16* xb   = (u16*)w; w += (size_t)16777216 * 2;  // x bf16 [8192][2048]
  u16* W1t  = (u16*)w; w += (size_t)4194304 * 2;   // W1^T bf16 [2048][2048]
  u16* hb   = (u16*)w; w += (size_t)16777216 * 2;  // relu(xW1+b1) bf16 [8192][2048]
  u16* Vb   = (u16*)w; w += (size_t)1048576 * 2;   // V bf16 [512][2048] (already B^T)
  u16* Ut   = (u16*)w; w += (size_t)1048576 * 2;   // U interleaved bf16 [2048][512]
  u16* wb   = (u16*)w; w += (size_t)4194304 * 2;   // alpha*vx bf16 [8192][512]
  float* alpha = (float*)w;                        // [8192][8]

  cvt_f32_bf16<<<8192, 256, 0, stream>>>(x, xb, 2097152);
  cvt_f32_bf16<<<512, 256, 0, stream>>>(V, Vb, 131072);
  transpose_cvt<<<dim3(64, 64), dim3(32, 8), 0, stream>>>(W1, W1t);
  make_Ut<<<4096, 256, 0, stream>>>(U, Ut);

  // h = relu(x @ W1 + b1)   [8192x2048x2048]
  gemm256<0><<<256, 512, 0, stream>>>(xb, W1t, nullptr, hb, b1, 8192, 2048, 2048);
  // alpha = softmax(h @ W2 + b2)
  router<<<2048, 256, 0, stream>>>(hb, W2, b2, alpha);
  // w = alpha ⊙ (x @ V^T)   [8192x512x2048]
  gemm_bt<1><<<256, 256, 0, stream>>>(xb, Vb, nullptr, wb, nullptr, alpha, 8192, 512, 2048);
  // out = w @ U'            [8192x2048x512]
  gemm256<2><<<256, 512, 0, stream>>>(wb, Ut, out, nullptr, nullptr, 8192, 2048, 512);
}

// Round 7
// 325.171 us; speedup vs baseline: 1.0338x; 1.0338x over previous
//
#include <hip/hip_runtime.h>

typedef unsigned short u16;
typedef unsigned int u32;
typedef __bf16 bf16x8 __attribute__((ext_vector_type(8)));
typedef float f32x4 __attribute__((ext_vector_type(4)));
typedef u16 u16x8 __attribute__((ext_vector_type(8)));

__device__ __forceinline__ u16 f2bf(float f) {
  u32 u = __builtin_bit_cast(u32, f);
  u += 0x7FFFu + ((u >> 16) & 1u);   // round-to-nearest-even
  return (u16)(u >> 16);
}
__device__ __forceinline__ float bf2f(u16 h) {
  u32 u = ((u32)h) << 16;
  return __builtin_bit_cast(float, u);
}

// async global->LDS, 16B per lane, linear dest (wave-uniform base + lane*16)
#define GLD16(gp, lp)                                                      \
  __builtin_amdgcn_global_load_lds(                                        \
      (const __attribute__((address_space(1))) void*)(gp),                 \
      (__attribute__((address_space(3))) void*)(lp), 16, 0, 0)

#define LGKM0()                                          \
  do {                                                   \
    asm volatile("s_waitcnt lgkmcnt(0)" ::: "memory");   \
    __builtin_amdgcn_sched_barrier(0);                   \
  } while (0)
#define VMCNT(n)                                              \
  do {                                                        \
    asm volatile("s_waitcnt vmcnt(" #n ")" ::: "memory");     \
    __builtin_amdgcn_sched_barrier(0);                        \
  } while (0)
#define BAR() __builtin_amdgcn_s_barrier()

// ---------------------------------------------------------------------------
// f32 -> bf16 elementwise convert, 8 elems/thread
__global__ void cvt_f32_bf16(const float* __restrict__ in, u16* __restrict__ out, int n8) {
  int i = blockIdx.x * 256 + threadIdx.x;
  if (i >= n8) return;
  const float4* p = (const float4*)in + (size_t)i * 2;
  float4 a = p[0], b = p[1];
  u16x8 o;
  o[0] = f2bf(a.x); o[1] = f2bf(a.y); o[2] = f2bf(a.z); o[3] = f2bf(a.w);
  o[4] = f2bf(b.x); o[5] = f2bf(b.y); o[6] = f2bf(b.z); o[7] = f2bf(b.w);
  *((u16x8*)out + i) = o;
}

// W1 (2048x2048 f32, [d][e]) -> W1t bf16 [e][d]  (tiled transpose)
__global__ void transpose_cvt(const float* __restrict__ W1, u16* __restrict__ W1t) {
  __shared__ float tile[32][33];
  const int tx = threadIdx.x;        // 0..31
  const int ty = threadIdx.y;        // 0..7
  const int e0 = blockIdx.x * 32, d0 = blockIdx.y * 32;
#pragma unroll
  for (int j = 0; j < 4; ++j)
    tile[ty + j * 8][tx] = W1[(size_t)(d0 + ty + j * 8) * 2048 + e0 + tx];
  __syncthreads();
#pragma unroll
  for (int j = 0; j < 4; ++j)
    W1t[(size_t)(e0 + ty + j * 8) * 2048 + d0 + tx] = f2bf(tile[tx][ty + j * 8]);
}

// U (K=8, D=2048, R=64 f32) -> Ut bf16 [d][k*64+r]   (B^T layout for GEMM3)
__global__ void make_Ut(const float* __restrict__ U, u16* __restrict__ Ut) {
  int idx = blockIdx.x * 256 + threadIdx.x;   // n*512 + (k*64+r), total 1048576
  int n = idx >> 9;
  int kr = idx & 511;
  int k = kr >> 6, r = kr & 63;
  Ut[idx] = f2bf(U[(size_t)k * 131072 + (size_t)n * 64 + r]);
}

// ---------------------------------------------------------------------------
// 256x256 bf16 MFMA GEMM, SOFTWARE-PIPELINED LDS reads (1 barrier / K-tile):
//   half A: [issue ds_reads k1 | MFMA k0 x 4n]   (reads complete under MFMA)
//   fence : lgkm0 + vmcnt0 + s_barrier + sched_barrier
//   half B: [issue ds_reads k0(t+1) | STAGE(t+2) | MFMA k1 x 4n]
// 8 waves (2M x 4N), per-wave 128x64 output, BK=64, 128KiB double-buffered LDS.
// EPI 0: +bias, relu, bf16 out    EPI 2: f32 out
template <int EPI>
__launch_bounds__(512, 2)
__global__ void gemm256(const u16* __restrict__ A, const u16* __restrict__ Bt,
                        float* __restrict__ Cf, u16* __restrict__ Cb,
                        const float* __restrict__ bias, int M, int N, int Kd) {
  // [buf][half-tile: 0=Ah0 1=Ah1 2=Bh0 3=Bh1][128 rows x 64 elems]
  __shared__ u16 lds[2][4][8192];

  const int nbx = N >> 8;
  const int nwg = (M >> 8) * nbx;
  int wg = blockIdx.x;
  wg = (wg & 7) * (nwg >> 3) + (wg >> 3);       // XCD swizzle (nwg % 8 == 0)
  const int bx = wg % nbx, by = wg / nbx;
  const int bm = by << 8, bn = bx << 8;

  const int tid = threadIdx.x;
  const int lane = tid & 63, wave = tid >> 6;
  const int wr = wave >> 2;                      // 0..1  (A half)
  const int wc = wave & 3;                       // 0..3
  const int hc = 2 + (wc >> 1);                  // B half-tile index (2 or 3)
  const int l15 = lane & 15, hi = lane >> 4;
  const int swz = l15 & 7;

  // staging offsets: thread stages two 16B chunks per half-tile, LINEAR dest,
  // pre-swizzled global source column (involution: slot ^= row&7)
  const int scol = ((tid & 7) ^ ((tid >> 3) & 7)) << 3;
  const size_t goff0 = (size_t)(tid >> 3) * Kd + scol;
  const size_t goff1 = goff0 + (size_t)64 * Kd;
  const int d0e = tid * 8, d1e = tid * 8 + 4096;

  const int NT = Kd >> 6;

  // frag read element offsets (within one half-tile buffer)
  int aidx[8], bidx[4];
#pragma unroll
  for (int m = 0; m < 8; ++m) aidx[m] = (m * 16 + l15) * 64;
#pragma unroll
  for (int n = 0; n < 4; ++n) bidx[n] = ((wc & 1) * 64 + n * 16 + l15) * 64;
  const int slot0 = ((0 * 4 + hi) ^ swz) << 3;   // ksub 0
  const int slot1 = ((1 * 4 + hi) ^ swz) << 3;   // ksub 1

  f32x4 acc[8][4];
#pragma unroll
  for (int m = 0; m < 8; ++m)
#pragma unroll
    for (int n = 0; n < 4; ++n) acc[m][n] = f32x4{0.f, 0.f, 0.f, 0.f};

#define STAGE(tt, ht)                                                          \
  do {                                                                         \
    const u16* g_ = ((ht) < 2 ? A + (size_t)(bm + ((ht) & 1) * 128) * Kd       \
                              : Bt + (size_t)(bn + ((ht) & 1) * 128) * Kd)     \
                    + (size_t)(tt) * 64;                                       \
    u16* l_ = &lds[(tt) & 1][(ht)][0];                                         \
    GLD16(g_ + goff0, l_ + d0e);                                               \
    GLD16(g_ + goff1, l_ + d1e);                                               \
  } while (0)

#define MFMA_ALL(av, bv)                                                       \
  _Pragma("unroll") for (int m = 0; m < 8; ++m)                                \
    _Pragma("unroll") for (int n = 0; n < 4; ++n)                              \
      acc[m][n] = __builtin_amdgcn_mfma_f32_16x16x32_bf16(av[m], bv[n], acc[m][n], 0, 0, 0);

  bf16x8 av0[8], bv0[4], av1[8], bv1[4];

  // prologue: stage tiles 0 and 1 (16 loads), wait tile 0, pre-read k0(tile 0)
  STAGE(0, 0); STAGE(0, 1); STAGE(0, 2); STAGE(0, 3);
  STAGE(1, 0); STAGE(1, 1); STAGE(1, 2); STAGE(1, 3);
  VMCNT(8);
  BAR();
  __builtin_amdgcn_sched_barrier(0);
  {
    const u16* As = &lds[0][wr][0];
    const u16* Bs = &lds[0][hc][0];
#pragma unroll
    for (int m = 0; m < 8; ++m) av0[m] = *(const bf16x8*)(As + aidx[m] + slot0);
#pragma unroll
    for (int n = 0; n < 4; ++n) bv0[n] = *(const bf16x8*)(Bs + bidx[n] + slot0);
  }

  for (int t = 0; t < NT; ++t) {
    const int b = t & 1;
    const u16* As = &lds[b][wr][0];
    const u16* Bs = &lds[b][hc][0];

    // ---- half A: issue k1 reads; MFMA k0 (compiler inserts counted lgkm
    //      waits for av0/bv0, letting the 12 new reads complete under MFMA)
#pragma unroll
    for (int m = 0; m < 8; ++m) av1[m] = *(const bf16x8*)(As + aidx[m] + slot1);
#pragma unroll
    for (int n = 0; n < 4; ++n) bv1[n] = *(const bf16x8*)(Bs + bidx[n] + slot1);
    __builtin_amdgcn_s_setprio(1);
    MFMA_ALL(av0, bv0);
    __builtin_amdgcn_s_setprio(0);

    // ---- fence: all tile-t reads drained (LDS of buf b free for overwrite),
    //      tile t+1 loads resident (issued a full iteration ago -> ~0 wait)
    LGKM0();
    VMCNT(0);
    BAR();
    __builtin_amdgcn_sched_barrier(0);

    // ---- half B: stage tile t+2 into buf b; pre-read k0 of tile t+1 from
    //      buf b^1; MFMA k1 runs over the reads/stages
    if (t + 2 < NT) { STAGE(t + 2, 0); STAGE(t + 2, 1); STAGE(t + 2, 2); STAGE(t + 2, 3); }
    if (t + 1 < NT) {
      const u16* As2 = &lds[b ^ 1][wr][0];
      const u16* Bs2 = &lds[b ^ 1][hc][0];
#pragma unroll
      for (int m = 0; m < 8; ++m) av0[m] = *(const bf16x8*)(As2 + aidx[m] + slot0);
#pragma unroll
      for (int n = 0; n < 4; ++n) bv0[n] = *(const bf16x8*)(Bs2 + bidx[n] + slot0);
    }
    __builtin_amdgcn_s_setprio(1);
    MFMA_ALL(av1, bv1);
    __builtin_amdgcn_s_setprio(0);
  }
#undef STAGE
#undef MFMA_ALL

  // epilogue: C/D layout col=lane&15, row=(lane>>4)*4+reg  [m89-verified]
#pragma unroll
  for (int m = 0; m < 8; ++m) {
    const int row0 = bm + wr * 128 + m * 16 + hi * 4;
#pragma unroll
    for (int n = 0; n < 4; ++n) {
      const int col = bn + wc * 64 + n * 16 + l15;
      f32x4 v = acc[m][n];
      if (EPI == 0) {
        const float bsv = bias[col];
#pragma unroll
        for (int j = 0; j < 4; ++j) {
          float tv = v[j] + bsv;
          tv = tv > 0.f ? tv : 0.f;
          Cb[(size_t)(row0 + j) * N + col] = f2bf(tv);
        }
      } else {
#pragma unroll
        for (int j = 0; j < 4; ++j)
          Cf[(size_t)(row0 + j) * N + col] = v[j];
      }
    }
  }
}

// ---------------------------------------------------------------------------
// 128x128 bf16 MFMA GEMM (m97 structure) — kept for GEMM2 (N=512).
// EPI 1: *alpha[row, col/64], bf16 out
template <int EPI>
__launch_bounds__(256, 2)
__global__ void gemm_bt(const u16* __restrict__ A, const u16* __restrict__ Bt,
                        float* __restrict__ Cf, u16* __restrict__ Cb,
                        const float* __restrict__ bias, const float* __restrict__ alpha,
                        int M, int N, int Kd) {
  __shared__ u16 As[128 * 64];
  __shared__ u16 Bs[128 * 64];

  const int nbx = N >> 7;
  const int nwg = (M >> 7) * nbx;
  int wg = blockIdx.x;
  wg = (wg & 7) * (nwg >> 3) + (wg >> 3);
  const int bx = wg % nbx, by = wg / nbx;
  const int bm = by << 7, bn = bx << 7;

  const int tid = threadIdx.x;
  const int lane = tid & 63, wave = tid >> 6;
  const int wr = wave >> 1, wc = wave & 1;
  const int l15 = lane & 15, hi = lane >> 4;
  const int swz7 = l15 & 7;

  f32x4 acc[4][4];
#pragma unroll
  for (int m = 0; m < 4; ++m)
#pragma unroll
    for (int n = 0; n < 4; ++n)
      acc[m][n] = f32x4{0.f, 0.f, 0.f, 0.f};

  const int srow = tid >> 3;
  const int swzc = ((tid & 7) ^ (srow & 7)) << 3;
  const size_t ldsBase = (size_t)wave * 64 * 8;

  int aBase[4], bBase[4];
#pragma unroll
  for (int m = 0; m < 4; ++m) {
    aBase[m] = (wr * 64 + m * 16 + l15) * 64;
    bBase[m] = (wc * 64 + m * 16 + l15) * 64;
  }

  const u16* Ag = A + (size_t)(bm + srow) * Kd + swzc;
  const u16* Bg = Bt + (size_t)(bn + srow) * Kd + swzc;

  for (int k0 = 0; k0 < Kd; k0 += 64) {
#pragma unroll
    for (int i = 0; i < 4; ++i) {
      GLD16(Ag + (size_t)(i * 32) * Kd + k0, (u16*)As + i * 2048 + ldsBase);
      GLD16(Bg + (size_t)(i * 32) * Kd + k0, (u16*)Bs + i * 2048 + ldsBase);
    }
    __syncthreads();
#pragma unroll
    for (int kk = 0; kk < 2; ++kk) {
      const int soff = ((kk * 4 + hi) ^ swz7) << 3;
      bf16x8 av[4], bv[4];
#pragma unroll
      for (int m = 0; m < 4; ++m) av[m] = *(const bf16x8*)(As + aBase[m] + soff);
#pragma unroll
      for (int n = 0; n < 4; ++n) bv[n] = *(const bf16x8*)(Bs + bBase[n] + soff);
#pragma unroll
      for (int m = 0; m < 4; ++m)
#pragma unroll
        for (int n = 0; n < 4; ++n)
          acc[m][n] = __builtin_amdgcn_mfma_f32_16x16x32_bf16(av[m], bv[n], acc[m][n], 0, 0, 0);
    }
    __syncthreads();
  }

#pragma unroll
  for (int m = 0; m < 4; ++m) {
    const int row0 = bm + wr * 64 + m * 16 + hi * 4;
#pragma unroll
    for (int n = 0; n < 4; ++n) {
      const int col = bn + wc * 64 + n * 16 + l15;
      f32x4 v = acc[m][n];
      if (EPI == 1) {
        const int e = col >> 6;
#pragma unroll
        for (int j = 0; j < 4; ++j) {
          float t = v[j] * alpha[(size_t)(row0 + j) * 8 + e];
          Cb[(size_t)(row0 + j) * N + col] = f2bf(t);
        }
      } else {
#pragma unroll
        for (int j = 0; j < 4; ++j)
          Cf[(size_t)(row0 + j) * N + col] = v[j];
      }
    }
  }
}

// ---------------------------------------------------------------------------
// router: logits[i,e] = sum_d h[i,d]*W2[d,e] + b2[e]; alpha = softmax_e
__global__ void router(const u16* __restrict__ hb, const float* __restrict__ W2,
                       const float* __restrict__ b2, float* __restrict__ alphaOut) {
  const int row = blockIdx.x * 4 + (threadIdx.x >> 6);
  const int lane = threadIdx.x & 63;
  const u16* h = hb + (size_t)row * 2048;
  float a8[8] = {0.f, 0.f, 0.f, 0.f, 0.f, 0.f, 0.f, 0.f};
#pragma unroll
  for (int it = 0; it < 4; ++it) {
    const int d0 = it * 512 + lane * 8;
    u16x8 hv = *(const u16x8*)(h + d0);
#pragma unroll
    for (int jj = 0; jj < 8; ++jj) {
      const float hf = bf2f(hv[jj]);
      const float4* wp = (const float4*)(W2 + (size_t)(d0 + jj) * 8);
      float4 w0 = wp[0], w1 = wp[1];
      a8[0] += hf * w0.x; a8[1] += hf * w0.y; a8[2] += hf * w0.z; a8[3] += hf * w0.w;
      a8[4] += hf * w1.x; a8[5] += hf * w1.y; a8[6] += hf * w1.z; a8[7] += hf * w1.w;
    }
  }
#pragma unroll
  for (int off = 32; off; off >>= 1)
#pragma unroll
    for (int e = 0; e < 8; ++e) a8[e] += __shfl_xor(a8[e], off);
  if (lane == 0) {
    float mx = -1e30f;
#pragma unroll
    for (int e = 0; e < 8; ++e) { a8[e] += b2[e]; mx = a8[e] > mx ? a8[e] : mx; }
    float s = 0.f;
#pragma unroll
    for (int e = 0; e < 8; ++e) { a8[e] = __expf(a8[e] - mx); s += a8[e]; }
    const float inv = 1.f / s;
#pragma unroll
    for (int e = 0; e < 8; ++e) alphaOut[(size_t)row * 8 + e] = a8[e] * inv;
  }
}

// ---------------------------------------------------------------------------
extern "C" void kernel_launch(void* const* d_in, const int* in_sizes, int n_in,
                              void* d_out, int out_size, void* d_ws, size_t ws_size,
                              hipStream_t stream) {
  const float* x  = (const float*)d_in[0];
  const float* U  = (const float*)d_in[1];
  const float* V  = (const float*)d_in[2];
  const float* W1 = (const float*)d_in[3];
  const float* b1 = (const float*)d_in[4];
  const float* W2 = (const float*)d_in[5];
  const float* b2 = (const float*)d_in[6];
  float* out = (float*)d_out;

  char* w = (char*)d_ws;
  u16* xb   = (u16*)w; w += (size_t)16777216 * 2;  // x bf16 [8192][2048]
  u16* W1t  = (u16*)w; w += (size_t)4194304 * 2;   // W1^T bf16 [2048][2048]
  u16* hb   = (u16*)w; w += (size_t)16777216 * 2;  // relu(xW1+b1) bf16 [8192][2048]
  u16* Vb   = (u16*)w; w += (size_t)1048576 * 2;   // V bf16 [512][2048] (already B^T)
  u16* Ut   = (u16*)w; w += (size_t)1048576 * 2;   // U interleaved bf16 [2048][512]
  u16* wb   = (u16*)w; w += (size_t)4194304 * 2;   // alpha*vx bf16 [8192][512]
  float* alpha = (float*)w;                        // [8192][8]

  cvt_f32_bf16<<<8192, 256, 0, stream>>>(x, xb, 2097152);
  cvt_f32_bf16<<<512, 256, 0, stream>>>(V, Vb, 131072);
  transpose_cvt<<<dim3(64, 64), dim3(32, 8), 0, stream>>>(W1, W1t);
  make_Ut<<<4096, 256, 0, stream>>>(U, Ut);

  // h = relu(x @ W1 + b1)   [8192x2048x2048]
  gemm256<0><<<256, 512, 0, stream>>>(xb, W1t, nullptr, hb, b1, 8192, 2048, 2048);
  // alpha = softmax(h @ W2 + b2)
  router<<<2048, 256, 0, stream>>>(hb, W2, b2, alpha);
  // w = alpha ⊙ (x @ V^T)   [8192x512x2048]
  gemm_bt<1><<<256, 256, 0, stream>>>(xb, Vb, nullptr, wb, nullptr, alpha, 8192, 512, 2048);
  // out = w @ U'            [8192x2048x512]
  gemm256<2><<<256, 512, 0, stream>>>(wb, Ut, out, nullptr, nullptr, 8192, 2048, 512);
}